// Round 5
// baseline (355.061 us; speedup 1.0000x reference)
//
#include <hip/hip_runtime.h>
#include <hip/hip_bf16.h>

#define NTOK 196
#define QTOK 49
#define CDIM 768
#define BSAMP 256
#define NCLS 701
#define NCLSP 704

typedef __attribute__((ext_vector_type(8))) short bf16x8;
typedef __attribute__((ext_vector_type(4))) float f32x4;

typedef __attribute__((address_space(1))) const unsigned char gas_u8;
typedef __attribute__((address_space(3))) unsigned char las_u8;

__device__ __forceinline__ void dma16(const void* g, void* l) {
  // 16B/lane direct global->LDS DMA; LDS dest = wave-uniform base + lane*16.
  __builtin_amdgcn_global_load_lds((gas_u8*)g, (las_u8*)l, 16, 0, 0);
}

__device__ __forceinline__ void add4(float4& a, const float4& b) {
  a.x += b.x; a.y += b.y; a.z += b.z; a.w += b.w;
}

// ---------------------------------------------------------------------------
// Kernel 1: streaming pass via async global->LDS DMA (bypasses the VGPR/L1
// return path that capped R1-R4 at ~4.3 B/cyc/CU). Block b = quarter q=b&3 of
// task b>>2 (49 tokens). Each wave owns 13/12 tokens and a PRIVATE 4-deep ring
// of 3 KB LDS token buffers -> no __syncthreads in the loop, no vmcnt(0)
// drain. Manual s_waitcnt vmcnt(9/6/3/0) keeps 12 KB in flight per wave
// (96 KB/CU at 2 blocks/CU). Reduction arithmetic bitwise-identical to R4
// (same quad-sum tree + butterfly) -> same M, same k downstream.
// Energies go to LDS in-loop (lgkmcnt only) so vmcnt bookkeeping stays exact.
// ---------------------------------------------------------------------------
__global__ __launch_bounds__(256, 2) void phaseA_kernel(const float* __restrict__ x1,
                                                        const float* __restrict__ x2,
                                                        float* __restrict__ Mg,
                                                        float* __restrict__ Sg) {
  const int b    = blockIdx.x;
  const int task = b >> 2;
  const int q    = b & 3;
  const int s    = task & 255;
  const int br   = task >> 8;
  const float* __restrict__ feats = (br ? x2 : x1) + (size_t)s * (NTOK * CDIM);
  const char*  qbase = (const char*)(feats + (size_t)(q * QTOK) * CDIM);

  const int tid  = threadIdx.x;
  const int lane = tid & 63;
  const int wv   = tid >> 6;   // 0..3

  __shared__ __align__(16) char stage[4 * 4 * 3072];   // [wave][ring of 4][3072 B]
  __shared__ float Men[QTOK + 3];
  __shared__ float colred[4][CDIM];

  char* wstage = stage + wv * (4 * 3072);
  const int n = (wv == 0) ? 13 : 12;   // wave handles local tokens L = wv + 4j

  float4 acc0 = {0,0,0,0}, acc1 = {0,0,0,0}, acc2 = {0,0,0,0};

  auto issue = [&](int j) {
    const char* g = qbase + (size_t)(wv + 4 * j) * (CDIM * 4) + lane * 16;
    char* l = wstage + (j & 3) * 3072;        // wave-uniform LDS base
    dma16(g,        l);
    dma16(g + 1024, l + 1024);
    dma16(g + 2048, l + 2048);
  };

  issue(0); issue(1); issue(2);               // 3-deep prologue
  for (int j = 0; j < n; ++j) {
    if (j + 3 < n) issue(j + 3);
    const int rem = n - 1 - j;                // tokens still in flight after j
    if (rem >= 3)      __builtin_amdgcn_s_waitcnt(0x0F79);  // vmcnt(9)
    else if (rem == 2) __builtin_amdgcn_s_waitcnt(0x0F76);  // vmcnt(6)
    else if (rem == 1) __builtin_amdgcn_s_waitcnt(0x0F73);  // vmcnt(3)
    else               __builtin_amdgcn_s_waitcnt(0x0F70);  // vmcnt(0)

    const char* lb = wstage + (j & 3) * 3072 + lane * 16;
    const float4 r0 = *(const float4*)(lb);
    const float4 r1 = *(const float4*)(lb + 1024);
    const float4 r2 = *(const float4*)(lb + 2048);
    add4(acc0, r0); add4(acc1, r1); add4(acc2, r2);
    float e = ((r0.x + r0.y) + (r0.z + r0.w))
            + ((r1.x + r1.y) + (r1.z + r1.w))
            + ((r2.x + r2.y) + (r2.z + r2.w));
    #pragma unroll
    for (int off = 32; off; off >>= 1) e += __shfl_xor(e, off);
    if (lane == 0) Men[wv + 4 * j] = e;       // LDS (lgkm), not global (vmcnt)
  }

  *(float4*)&colred[wv][lane * 4      ] = acc0;
  *(float4*)&colred[wv][lane * 4 + 256] = acc1;
  *(float4*)&colred[wv][lane * 4 + 512] = acc2;
  __syncthreads();
  if (tid < QTOK) Mg[(size_t)task * NTOK + q * QTOK + tid] = Men[tid];
  for (int c = tid; c < CDIM; c += 256) {
    Sg[(size_t)b * CDIM + c] = (colred[0][c] + colred[1][c])
                             + (colred[2][c] + colred[3][c]);
  }
}

// ---------------------------------------------------------------------------
// Kernel 2: per-task rank/split + phase C (unchanged from R4, passing).
// ---------------------------------------------------------------------------
__global__ __launch_bounds__(256) void sgm2_kernel(const float* __restrict__ x1,
                                                   const float* __restrict__ x2,
                                                   const float* __restrict__ Mg,
                                                   const float* __restrict__ Sg,
                                                   __hip_bfloat16* __restrict__ Vb) {
  const int task = blockIdx.x;
  const int s  = task & 255;
  const int br = task >> 8;
  const float* __restrict__ feats = (br ? x2 : x1) + (size_t)s * (NTOK * CDIM);

  const int tid  = threadIdx.x;
  const int lane = tid & 63;
  const int wv   = tid >> 6;   // 0..3

  __shared__ float Msh[NTOK];
  __shared__ float Mn[NTOK];
  __shared__ float sortedv[NTOK];
  __shared__ int   rnk[NTOK];
  __shared__ int   list[NTOK];
  __shared__ float redmin[4], redmax[4];
  __shared__ int   kSh;
  __shared__ int   cntSh;
  __shared__ float partT[4][CDIM];

  if (tid < NTOK) Msh[tid] = Mg[(size_t)task * NTOK + tid];
  if (tid == 0) cntSh = 0;

  float srow[3];
  #pragma unroll
  for (int j = 0; j < 3; j++) {
    const int c = tid + j * 256;
    const float* sq = Sg + (size_t)(task * 4) * CDIM + c;
    srow[j] = (sq[0] + sq[CDIM]) + (sq[2 * CDIM] + sq[3 * CDIM]);
  }
  __syncthreads();

  float vmn = (tid < NTOK) ? Msh[tid] :  1e30f;
  float vmx = (tid < NTOK) ? Msh[tid] : -1e30f;
  #pragma unroll
  for (int off = 32; off; off >>= 1) {
    vmn = fminf(vmn, __shfl_xor(vmn, off));
    vmx = fmaxf(vmx, __shfl_xor(vmx, off));
  }
  if (lane == 0) { redmin[wv] = vmn; redmax[wv] = vmx; }
  __syncthreads();
  float mn = redmin[0], mx = redmax[0];
  #pragma unroll
  for (int i = 1; i < 4; i++) { mn = fminf(mn, redmin[i]); mx = fmaxf(mx, redmax[i]); }
  const float rng = mx - mn;
  if (tid < NTOK) Mn[tid] = (Msh[tid] - mn) / rng;
  __syncthreads();

  if (tid < NTOK) {
    const float mv = Mn[tid];
    int r = 0;
    for (int u = 0; u < NTOK; u++) {
      const float o = Mn[u];
      r += (o < mv) || (o == mv && u < tid);
    }
    sortedv[r] = mv;
    rnk[tid] = r;
  }
  __syncthreads();

  if (tid < 64) {
    float bd = -1.0f; int bj = NTOK;
    for (int j = lane; j < NTOK - 1; j += 64) {
      const float sj = sortedv[j];
      const float d = (sj == 0.0f) ? 0.0f : (sortedv[j + 1] - sj);
      if (d > bd || (d == bd && j < bj)) { bd = d; bj = j; }
    }
    #pragma unroll
    for (int off = 32; off; off >>= 1) {
      const float od = __shfl_xor(bd, off);
      const int   oj = __shfl_xor(bj, off);
      if (od > bd || (od == bd && oj < bj)) { bd = od; bj = oj; }
    }
    if (lane == 0) kSh = bj;
  }
  __syncthreads();

  const int k = kSh;
  const bool takeFg = (k <= NTOK / 2);

  if (tid < NTOK) {
    const int r = rnk[tid];
    const bool inSet = takeFg ? (r < k) : (r >= k);
    if (inSet) { int p = atomicAdd(&cntSh, 1); list[p] = tid; }
  }
  __syncthreads();
  const int m = cntSh;

  float4 t0a = {0,0,0,0}, t1a = {0,0,0,0}, t2a = {0,0,0,0};
  const float* lanebase = feats + lane * 4;
  for (int i0 = wv * 4; i0 < m; i0 += 16) {
    const int nb = m - i0;
    float4 r[4][3];
    #pragma unroll
    for (int j = 0; j < 4; j++) {
      if (j < nb) {
        const int tk = list[i0 + j];
        const float* p = lanebase + (size_t)tk * CDIM;
        #pragma unroll
        for (int g = 0; g < 3; g++) r[j][g] = *(const float4*)(p + g * 256);
      }
    }
    #pragma unroll
    for (int j = 0; j < 4; j++) {
      if (j < nb) { add4(t0a, r[j][0]); add4(t1a, r[j][1]); add4(t2a, r[j][2]); }
    }
  }

  *(float4*)&partT[wv][lane * 4      ] = t0a;
  *(float4*)&partT[wv][lane * 4 + 256] = t1a;
  *(float4*)&partT[wv][lane * 4 + 512] = t2a;
  __syncthreads();

  const float fgc = (float)(k > 1 ? k : 1);
  const float bgc = (float)((NTOK - k) > 1 ? (NTOK - k) : 1);
  const size_t rowFg = (size_t)(2 * br + 1) * BSAMP + s;
  const size_t rowBg = (size_t)(2 * br    ) * BSAMP + s;
  #pragma unroll
  for (int j = 0; j < 3; j++) {
    const int c = tid + j * 256;
    const float T = (partT[0][c] + partT[1][c]) + (partT[2][c] + partT[3][c]);
    const float S = srow[j];
    float fg, bg;
    if (takeFg) { fg = T;     bg = S - T; }
    else        { bg = T;     fg = S - T; }
    Vb[rowFg * CDIM + c] = __float2bfloat16(fg / fgc);
    Vb[rowBg * CDIM + c] = __float2bfloat16(bg / bgc);
  }
}

// W [768][701] fp32 -> WT [704][768] bf16 (rows 701..703 zero-padded).
__global__ __launch_bounds__(256) void wt_kernel(const float* __restrict__ W,
                                                 __hip_bfloat16* __restrict__ WT) {
  __shared__ float tile[32][33];
  const int c0 = blockIdx.x * 32;
  const int k0 = blockIdx.y * 32;
  const int tx = threadIdx.x & 31;
  const int ty = threadIdx.x >> 5;
  #pragma unroll
  for (int i = 0; i < 4; i++) {
    const int kr = ty + i * 8;
    const int c = c0 + tx;
    tile[kr][tx] = (c < NCLS) ? W[(size_t)(k0 + kr) * NCLS + c] : 0.0f;
  }
  __syncthreads();
  #pragma unroll
  for (int i = 0; i < 4; i++) {
    const int cr = ty + i * 8;
    const int cls = c0 + cr;
    WT[(size_t)cls * CDIM + k0 + tx] = __float2bfloat16(tile[tx][cr]);
  }
}

// Vb [1024][768] bf16 x WT [704][768] bf16 -> out [1024][701] fp32 (+bias).
__global__ __launch_bounds__(256) void mfma_gemm(const __hip_bfloat16* __restrict__ Vb,
                                                 const __hip_bfloat16* __restrict__ WT,
                                                 const float* __restrict__ bias,
                                                 float* __restrict__ out) {
  const int w = blockIdx.x * 4 + (threadIdx.x >> 6);
  const int lane = threadIdx.x & 63;
  const int tr = w / (NCLSP / 16);
  const int tc = w % (NCLSP / 16);
  const int m0 = tr * 16;
  const int n0 = tc * 16;
  const int ko = (lane >> 4) * 8;

  const short* aptr = (const short*)Vb + (size_t)(m0 + (lane & 15)) * CDIM + ko;
  const short* bptr = (const short*)WT + (size_t)(n0 + (lane & 15)) * CDIM + ko;

  f32x4 acc = {0.f, 0.f, 0.f, 0.f};
  #pragma unroll
  for (int k0 = 0; k0 < CDIM; k0 += 32) {
    const bf16x8 af = *(const bf16x8*)(aptr + k0);
    const bf16x8 bf = *(const bf16x8*)(bptr + k0);
    acc = __builtin_amdgcn_mfma_f32_16x16x32_bf16(af, bf, acc, 0, 0, 0);
  }

  const int crow = m0 + (lane >> 4) * 4;
  const int ccol = n0 + (lane & 15);
  if (ccol < NCLS) {
    const float bv = bias[ccol];
    #pragma unroll
    for (int r = 0; r < 4; r++)
      out[(size_t)(crow + r) * NCLS + ccol] = acc[r] + bv;
  }
}

extern "C" void kernel_launch(void* const* d_in, const int* in_sizes, int n_in,
                              void* d_out, int out_size, void* d_ws, size_t ws_size,
                              hipStream_t stream) {
  const float* x1 = (const float*)d_in[0];
  const float* x2 = (const float*)d_in[1];
  const float* W  = (const float*)d_in[2];
  const float* b  = (const float*)d_in[3];
  float* out = (float*)d_out;

  char* ws = (char*)d_ws;
  __hip_bfloat16* Vb = (__hip_bfloat16*)ws;                      // 1,572,864 B
  __hip_bfloat16* WT = (__hip_bfloat16*)(ws + 1572864);          // 1,081,344 B
  float* Mg = (float*)(ws + 1572864 + 1081344);                  //   401,408 B
  float* Sg = (float*)(ws + 1572864 + 1081344 + 401408);         // 6,291,456 B

  phaseA_kernel<<<2048, 256, 0, stream>>>(x1, x2, Mg, Sg);
  sgm2_kernel<<<512, 256, 0, stream>>>(x1, x2, Mg, Sg, Vb);
  wt_kernel<<<dim3(22, 24), 256, 0, stream>>>(W, WT);
  mfma_gemm<<<704, 256, 0, stream>>>(Vb, WT, b, out);
}